// Round 10
// baseline (91.891 us; speedup 1.0000x reference)
//
#include <hip/hip_runtime.h>

typedef short bf16x8 __attribute__((ext_vector_type(8)));
typedef float f32x16 __attribute__((ext_vector_type(16)));

#define BIG_F 1e10f
constexpr int B = 16;
constexpr int N = 4096;
constexpr int ROWS = 128;         // x-rows per block
constexpr int COLS = 512;         // y-cols per block
constexpr int NRB = N / ROWS;     // 32 row-blocks
constexpr int NCB = N / COLS;     // 8 col-blocks

// truncating bf16 hi/lo split: v ~= hi + lo
__device__ __forceinline__ void split(float v, unsigned& h, unsigned& l) {
    unsigned hb = __float_as_uint(v) & 0xFFFF0000u;
    h = hb >> 16;
    float r = v - __uint_as_float(hb);
    l = __float_as_uint(r) >> 16;
}

__device__ __forceinline__ float min3f(float a, float b, float c) {
    return fminf(fminf(a, b), c);   // fuses to v_min3_f32
}

__device__ __forceinline__ float vmin16(f32x16 C) {
    float u0 = min3f(C[0], C[1], C[2]);
    float u1 = min3f(C[3], C[4], C[5]);
    float u2 = min3f(C[6], C[7], C[8]);
    float u3 = min3f(C[9], C[10], C[11]);
    float u4 = min3f(C[12], C[13], C[14]);
    return min3f(min3f(u0, u1, u2), fminf(u3, u4), C[15]);
}

__device__ __forceinline__ float4 min4(float4 a, float4 b) {
    return make_float4(fminf(a.x, b.x), fminf(a.y, b.y),
                       fminf(a.z, b.z), fminf(a.w, b.w));
}

// VALU-pipe cross-lane min via DPP (no ds-op). ctrl must be a literal.
// Validated exact in R8/R9 (absmax 0).
#define DPP_MIN(v, ctrl)                                                      \
    v = fminf(v, __int_as_float(__builtin_amdgcn_update_dpp(                  \
            __float_as_int(v), __float_as_int(v), (ctrl), 0xF, 0xF, false)))

// P[n,m] = xx[n] + yy[m] - 2 x_n . y_m (+BIG masked) via mfma_f32_32x32x16_bf16:
//   A_k(n) = [ah0..2, ah0..2, al0..2, al0..2, xxh, xxl, 1, 1]  (ah+al = -2x)
//   B_k(m) = [yh0..2, yl0..2, yh0..2, yl0..2, 1, 1, qh, ql]    (qh+ql = yy)
// One 128x512 job per block (grid 4096), lean register shape (R5/R9 lineage —
// the only shape that holds (256,4) without spill; R3/R8 heavier bodies
// collapsed to 64-VGPR + GBs of scratch).
// R10 change: 1-deep B-fragment PREFETCH pipeline (nb0/nb1, +8 VGPR) — R9's
// unroll-1 loop serialized 2x ~120cy ds_read latency per iteration (8x on the
// critical path = the ~42us chamfer invariant across R2/R4/R5/R9).
__global__ __launch_bounds__(256, 4) void chamfer_mfma(
    const float* __restrict__ x, const float* __restrict__ y,
    const int* __restrict__ mask,
    float* __restrict__ rowpart,   // [B][NCB][2][N] row-min partials (sset slabs)
    float* __restrict__ colpart,   // [B][NRB][N]    col-min partials (128 rows)
    float* __restrict__ out)
{
    const int rb = blockIdx.x & 31;   // consecutive blocks share the y-slice (L2)
    const int cb = blockIdx.x >> 5;
    const int b  = blockIdx.y;
    const int t  = threadIdx.x;

    __shared__ __align__(16) unsigned short Bpack[2][COLS][8];  // 16 KB
    __shared__ float colbuf[8][COLS];                           // 16 KB

    if (blockIdx.x == 0 && b == 0 && t == 0) out[0] = 0.0f;  // finalize is next

    const float* xb = x + (size_t)b * 3 * N;
    const float* yb = y + (size_t)b * 3 * N;
    const int*   mb = mask + b * N;

    // ---- pack this block's 512-col B slice (2 points/thread) ----
#pragma unroll
    for (int i = 0; i < 2; ++i) {
        int c = t + i * 256;
        int m = cb * COLS + c;
        float y0 = yb[m], y1 = yb[N + m], y2 = yb[2 * N + m];
        float madd = mb[m] ? 0.0f : BIG_F;
        float yy = fmaf(y2, y2, fmaf(y1, y1, y0 * y0)) + madd;
        unsigned h0, l0, h1, l1, h2, l2, qh, ql;
        split(y0, h0, l0);
        split(y1, h1, l1);
        split(y2, h2, l2);
        split(yy, qh, ql);
        unsigned u0 = h0 | (h1 << 16);
        unsigned u1 = h2 | (l0 << 16);
        unsigned u2 = l1 | (l2 << 16);
        uint4 w0 = { u0, u1, u2, u0 };
        uint4 w1 = { u1, u2, 0x3F803F80u, qh | (ql << 16) };
        *(uint4*)&Bpack[0][c][0] = w0;
        *(uint4*)&Bpack[1][c][0] = w1;
    }

    const int w    = t >> 6;    // wave 0..3, rows w*32..w*32+31
    const int L    = t & 63;
    const int half = L >> 5;    // k-half 0/1
    const int lc   = L & 31;

    // ---- A fragment built in-register for own row (no LDS, no barrier) ----
    bf16x8 afr;
    {
        int n = rb * ROWS + w * 32 + lc;
        float x0 = xb[n], x1 = xb[N + n], x2 = xb[2 * N + n];
        float madd = mb[n] ? 0.0f : BIG_F;
        float xx = fmaf(x2, x2, fmaf(x1, x1, x0 * x0)) + madd;
        unsigned h0, l0, h1, l1, h2, l2, xh, xl;
        split(-2.0f * x0, h0, l0);
        split(-2.0f * x1, h1, l1);
        split(-2.0f * x2, h2, l2);
        split(xx, xh, xl);
        uint4 wa;
        wa.x = half ? (l2 | (l0 << 16)) : (h0 | (h1 << 16));
        wa.y = half ? (l1 | (l2 << 16)) : (h2 | (h0 << 16));
        wa.z = half ? (xh | (xl << 16)) : (h1 | (h2 << 16));
        wa.w = half ? 0x3F803F80u       : (l0 | (l1 << 16));
        afr = *(bf16x8*)&wa;
    }

    __syncthreads();

    const unsigned short* Bb = &Bpack[half][lc][0];  // +p*512 shorts = col p*64+lc

    float rm[16];
#pragma unroll
    for (int r = 0; r < 16; ++r) rm[r] = 1e30f;

    const f32x16 z16 = {0.f,0.f,0.f,0.f,0.f,0.f,0.f,0.f,
                        0.f,0.f,0.f,0.f,0.f,0.f,0.f,0.f};

    // prime the 1-deep pipeline with p=0's fragments
    bf16x8 nb0 = *(const bf16x8*)(Bb);
    bf16x8 nb1 = *(const bf16x8*)(Bb + 256);

#pragma unroll 1
    for (int p = 0; p < 8; ++p) {          // 8 col-pairs of 32 = 512 cols
        bf16x8 bf0 = nb0, bf1 = nb1;
        // prefetch next pair NOW — ds latency hides under MFMA + min work
        int pn = (p + 1) & 7;              // p=7 harmlessly re-reads p=0
        nb0 = *(const bf16x8*)(Bb + pn * 512);
        nb1 = *(const bf16x8*)(Bb + pn * 512 + 256);

        f32x16 C0 = __builtin_amdgcn_mfma_f32_32x32x16_bf16(afr, bf0, z16, 0, 0, 0);
        f32x16 C1 = __builtin_amdgcn_mfma_f32_32x32x16_bf16(afr, bf1, z16, 0, 0, 0);
        // C[r]: row = w*32 + (r&3)+8*(r>>2)+4*half, col = p*64(+32)+lc
#pragma unroll
        for (int r = 0; r < 16; ++r) rm[r] = min3f(rm[r], C0[r], C1[r]);
        // col partials over this half's 16 rows -> LDS (no shfl on critical path)
        colbuf[w * 2 + half][p * 64 + lc]      = vmin16(C0);
        colbuf[w * 2 + half][p * 64 + 32 + lc] = vmin16(C1);
    }

    // ---- row-min over each 16-lane group, entirely on the VALU pipe ----
#pragma unroll
    for (int r = 0; r < 16; ++r) {
        DPP_MIN(rm[r], 0xB1);    // quad_perm {1,0,3,2}  = xor1
        DPP_MIN(rm[r], 0x4E);    // quad_perm {2,3,0,1}  = xor2
        DPP_MIN(rm[r], 0x124);   // row_ror:4
        DPP_MIN(rm[r], 0x128);   // row_ror:8
    }
    if ((lc & 15) == 0) {        // lanes 0,16,32,48: (half, col-subset)
        int sset = lc >> 4;      // min over cols with (c&63) in sset*16+[0,15]+{0,32}
        float* rp = rowpart + (((size_t)(b * NCB + cb)) * 2 + sset) * N
                  + rb * ROWS + w * 32 + half * 4;
        *(float4*)(rp +  0) = make_float4(rm[0],  rm[1],  rm[2],  rm[3]);
        *(float4*)(rp +  8) = make_float4(rm[4],  rm[5],  rm[6],  rm[7]);
        *(float4*)(rp + 16) = make_float4(rm[8],  rm[9],  rm[10], rm[11]);
        *(float4*)(rp + 24) = make_float4(rm[12], rm[13], rm[14], rm[15]);
    }

    __syncthreads();
    if (t < 128) {                   // combine 8 (wave,half) slabs, float4-wide
        const float4* cb4 = (const float4*)&colbuf[0][0];
        float4 v = cb4[t];
#pragma unroll
        for (int s = 1; s < 8; ++s) v = min4(v, cb4[s * 128 + t]);
        *(float4*)(colpart + ((size_t)b * NRB + rb) * N + cb * COLS + t * 4) = v;
    }
}

// Merged, deeply-unrolled slab fold: 16 independent loads in flight per batch
// (R9's two unroll-4 loops left only 4 outstanding -> ~6.5us latency-bound).
__global__ __launch_bounds__(256) void finalize_kernel(
    const int* __restrict__ mask,
    const float* __restrict__ rowpart, const float* __restrict__ colpart,
    float* __restrict__ out)
{
    const int b = blockIdx.x & 15;
    const int q = blockIdx.x >> 4;   // quarter 0..3
    const int t = threadIdx.x;
    const int* mrow = mask + b * N;

    int cnt = 0;
    for (int i = t; i < N / 4; i += 256) {
        int4 mk = ((const int4*)mrow)[i];
        cnt += mk.x + mk.y + mk.z + mk.w;
    }

    const int p0 = q * 1024 + t * 4;
    const float* cp = colpart + (size_t)b * NRB * N + p0;      // 32 slabs
    const float* rp = rowpart + (size_t)b * NCB * 2 * N + p0;  // 16 slabs

    float4 mn = *(const float4*)cp;
    float4 rn = *(const float4*)rp;
#pragma unroll 8
    for (int pb = 1; pb < NRB; ++pb) {
        mn = min4(mn, *(const float4*)(cp + (size_t)pb * N));
        if (pb < NCB * 2)
            rn = min4(rn, *(const float4*)(rp + (size_t)pb * N));
    }
    int4 mk = *(const int4*)(mrow + p0);
    float s = (mk.x ? (mn.x + rn.x) : 0.f) + (mk.y ? (mn.y + rn.y) : 0.f)
            + (mk.z ? (mn.z + rn.z) : 0.f) + (mk.w ? (mn.w + rn.w) : 0.f);

    for (int off = 32; off > 0; off >>= 1) {
        s   += __shfl_down(s, off);
        cnt += __shfl_down(cnt, off);
    }
    __shared__ float rs[4];
    __shared__ int   rc[4];
    const int wv = t >> 6;
    if ((t & 63) == 0) { rs[wv] = s; rc[wv] = cnt; }
    __syncthreads();
    if (t == 0) {
        float S = rs[0] + rs[1] + rs[2] + rs[3];
        float C = (float)(rc[0] + rc[1] + rc[2] + rc[3]);
        atomicAdd(out, (S / C) * (1.0f / 16.0f));
    }
}

extern "C" void kernel_launch(void* const* d_in, const int* in_sizes, int n_in,
                              void* d_out, int out_size, void* d_ws, size_t ws_size,
                              hipStream_t stream) {
    const float* x    = (const float*)d_in[0];
    const float* y    = (const float*)d_in[1];
    const int*   mask = (const int*)d_in[2];

    float* rowpart = (float*)d_ws;                        // B*NCB*2*N = 4 MB
    float* colpart = rowpart + (size_t)B * NCB * 2 * N;   // B*NRB*N   = 8 MB

    chamfer_mfma<<<dim3(NRB * NCB, B), 256, 0, stream>>>(
        x, y, mask, rowpart, colpart, (float*)d_out);
    finalize_kernel<<<dim3(64), 256, 0, stream>>>(
        mask, rowpart, colpart, (float*)d_out);
}

// Round 11
// 86.913 us; speedup vs baseline: 1.0573x; 1.0573x over previous
//
#include <hip/hip_runtime.h>

typedef short bf16x8 __attribute__((ext_vector_type(8)));
typedef float f32x16 __attribute__((ext_vector_type(16)));

#define BIG_F 1e10f
constexpr int B = 16;
constexpr int N = 4096;
constexpr int COLS = 512;           // y-cols per block
constexpr int NCB = N / COLS;       // 8 col-blocks
constexpr int JOBS = 4;             // 128-row jobs per block
constexpr int SUBROWS = 128 * JOBS; // 512 rows per block
constexpr int NSB = N / SUBROWS;    // 8 row-superblocks

// truncating bf16 hi/lo split: v ~= hi + lo
__device__ __forceinline__ void split(float v, unsigned& h, unsigned& l) {
    unsigned hb = __float_as_uint(v) & 0xFFFF0000u;
    h = hb >> 16;
    float r = v - __uint_as_float(hb);
    l = __float_as_uint(r) >> 16;
}

__device__ __forceinline__ float min3f(float a, float b, float c) {
    return fminf(fminf(a, b), c);   // fuses to v_min3_f32
}

__device__ __forceinline__ float vmin16(f32x16 C) {
    float u0 = min3f(C[0], C[1], C[2]);
    float u1 = min3f(C[3], C[4], C[5]);
    float u2 = min3f(C[6], C[7], C[8]);
    float u3 = min3f(C[9], C[10], C[11]);
    float u4 = min3f(C[12], C[13], C[14]);
    return min3f(min3f(u0, u1, u2), fminf(u3, u4), C[15]);
}

__device__ __forceinline__ float4 min4(float4 a, float4 b) {
    return make_float4(fminf(a.x, b.x), fminf(a.y, b.y),
                       fminf(a.z, b.z), fminf(a.w, b.w));
}

// VALU-pipe cross-lane min via DPP (no ds-op). Validated exact (R8/R9).
#define DPP_MIN(v, ctrl)                                                      \
    v = fminf(v, __int_as_float(__builtin_amdgcn_update_dpp(                  \
            __float_as_int(v), __float_as_int(v), (ctrl), 0xF, 0xF, false)))

// P[n,m] = xx[n] + yy[m] - 2 x_n . y_m (+BIG masked) via mfma_f32_32x32x16_bf16:
//   A_k(n) = [ah0..2, ah0..2, al0..2, al0..2, xxh, xxl, 1, 1]  (ah+al = -2x)
//   B_k(m) = [yh0..2, yl0..2, yh0..2, yl0..2, 1, 1, qh, ql]    (qh+ql = yy)
// R11: chamfer time has been invariant (~42us) across 512/2048/4096-block
// structures -> per-block fixed latency x generations dominates, not the
// inner loop. Grid 1024 (ONE resident generation, 4 blocks/CU); each block
// packs its B-slice once and runs 4 row-jobs. Per-job body keeps the ONLY
// register shape proven spill-free at (256,4): rm[16] + one C-pair, unroll 1
// (R3/R8: heavier bodies -> 64-VGPR spill collapse). Col-mins accumulate in
// thread-owned LDS slots (rmw by writer, race-free) instead of R8's cm[16];
// 2 barriers per block total.
__global__ __launch_bounds__(256, 4) void chamfer_mfma(
    const float* __restrict__ x, const float* __restrict__ y,
    const int* __restrict__ mask,
    float* __restrict__ rowpart,   // [B][NCB][2][N] row-min partials (sset slabs)
    float* __restrict__ colpart,   // [B][NSB][N]    col-min partials (512 rows)
    float* __restrict__ out)
{
    const int blk = blockIdx.x;     // 0..1023
    const int b   = blk >> 6;
    const int cb  = (blk >> 3) & 7;
    const int sub = blk & 7;
    const int t   = threadIdx.x;

    __shared__ __align__(16) unsigned short Bpack[2][COLS][8];  // 16 KB
    __shared__ float colbuf[8][COLS];                           // 16 KB

    if (blk == 0 && t == 0) out[0] = 0.0f;   // finalize is the next dispatch

    const float* xb = x + (size_t)b * 3 * N;
    const float* yb = y + (size_t)b * 3 * N;
    const int*   mb = mask + b * N;

    // ---- pack this block's 512-col B slice (2 points/thread) ----
#pragma unroll
    for (int i = 0; i < 2; ++i) {
        int c = t + i * 256;
        int m = cb * COLS + c;
        float y0 = yb[m], y1 = yb[N + m], y2 = yb[2 * N + m];
        float madd = mb[m] ? 0.0f : BIG_F;
        float yy = fmaf(y2, y2, fmaf(y1, y1, y0 * y0)) + madd;
        unsigned h0, l0, h1, l1, h2, l2, qh, ql;
        split(y0, h0, l0);
        split(y1, h1, l1);
        split(y2, h2, l2);
        split(yy, qh, ql);
        unsigned u0 = h0 | (h1 << 16);
        unsigned u1 = h2 | (l0 << 16);
        unsigned u2 = l1 | (l2 << 16);
        uint4 w0 = { u0, u1, u2, u0 };
        uint4 w1 = { u1, u2, 0x3F803F80u, qh | (ql << 16) };
        *(uint4*)&Bpack[0][c][0] = w0;
        *(uint4*)&Bpack[1][c][0] = w1;
    }

    const int w    = t >> 6;    // wave 0..3, rows w*32..w*32+31 within a job
    const int L    = t & 63;
    const int half = L >> 5;    // k-half 0/1
    const int lc   = L & 31;

    __syncthreads();

    const unsigned short* Bb = &Bpack[half][lc][0];  // +p*512 shorts = col p*64+lc
    float* cacc0 = &colbuf[w * 2 + half][lc];        // thread-owned col-min slots

    const f32x16 z16 = {0.f,0.f,0.f,0.f,0.f,0.f,0.f,0.f,
                        0.f,0.f,0.f,0.f,0.f,0.f,0.f,0.f};

#pragma unroll 1
    for (int jj = 0; jj < JOBS; ++jj) {
        // ---- A fragment built in-register for this job's row ----
        bf16x8 afr;
        {
            int n = sub * SUBROWS + jj * 128 + w * 32 + lc;
            float x0 = xb[n], x1 = xb[N + n], x2 = xb[2 * N + n];
            float madd = mb[n] ? 0.0f : BIG_F;
            float xx = fmaf(x2, x2, fmaf(x1, x1, x0 * x0)) + madd;
            unsigned h0, l0, h1, l1, h2, l2, xh, xl;
            split(-2.0f * x0, h0, l0);
            split(-2.0f * x1, h1, l1);
            split(-2.0f * x2, h2, l2);
            split(xx, xh, xl);
            uint4 wa;
            wa.x = half ? (l2 | (l0 << 16)) : (h0 | (h1 << 16));
            wa.y = half ? (l1 | (l2 << 16)) : (h2 | (h0 << 16));
            wa.z = half ? (xh | (xl << 16)) : (h1 | (h2 << 16));
            wa.w = half ? 0x3F803F80u       : (l0 | (l1 << 16));
            afr = *(bf16x8*)&wa;
        }

        float rm[16];
#pragma unroll
        for (int r = 0; r < 16; ++r) rm[r] = 1e30f;

        bf16x8 nb0 = *(const bf16x8*)(Bb);
        bf16x8 nb1 = *(const bf16x8*)(Bb + 256);

#pragma unroll 1
        for (int p = 0; p < 8; ++p) {          // 8 col-pairs of 32 = 512 cols
            bf16x8 bf0 = nb0, bf1 = nb1;
            int pn = (p + 1) & 7;              // p=7 harmlessly re-reads p=0
            nb0 = *(const bf16x8*)(Bb + pn * 512);
            nb1 = *(const bf16x8*)(Bb + pn * 512 + 256);

            f32x16 C0 = __builtin_amdgcn_mfma_f32_32x32x16_bf16(afr, bf0, z16, 0, 0, 0);
            f32x16 C1 = __builtin_amdgcn_mfma_f32_32x32x16_bf16(afr, bf1, z16, 0, 0, 0);
            // C[r]: row = w*32 + (r&3)+8*(r>>2)+4*half, col = p*64(+32)+lc
#pragma unroll
            for (int r = 0; r < 16; ++r) rm[r] = min3f(rm[r], C0[r], C1[r]);
            // col-min accumulation in thread-owned LDS slots (rmw, race-free)
            float v0 = vmin16(C0), v1 = vmin16(C1);
            if (jj == 0) {
                cacc0[p * 64]      = v0;
                cacc0[p * 64 + 32] = v1;
            } else {
                cacc0[p * 64]      = fminf(cacc0[p * 64],      v0);
                cacc0[p * 64 + 32] = fminf(cacc0[p * 64 + 32], v1);
            }
        }

        // ---- row-min over each 16-lane group, entirely on the VALU pipe ----
#pragma unroll
        for (int r = 0; r < 16; ++r) {
            DPP_MIN(rm[r], 0xB1);    // quad_perm {1,0,3,2}  = xor1
            DPP_MIN(rm[r], 0x4E);    // quad_perm {2,3,0,1}  = xor2
            DPP_MIN(rm[r], 0x124);   // row_ror:4
            DPP_MIN(rm[r], 0x128);   // row_ror:8
        }
        if ((lc & 15) == 0) {        // lanes 0,16,32,48: (half, col-subset)
            int sset = lc >> 4;
            float* rp = rowpart + (((size_t)(b * NCB + cb)) * 2 + sset) * N
                      + sub * SUBROWS + jj * 128 + w * 32 + half * 4;
            *(float4*)(rp +  0) = make_float4(rm[0],  rm[1],  rm[2],  rm[3]);
            *(float4*)(rp +  8) = make_float4(rm[4],  rm[5],  rm[6],  rm[7]);
            *(float4*)(rp + 16) = make_float4(rm[8],  rm[9],  rm[10], rm[11]);
            *(float4*)(rp + 24) = make_float4(rm[12], rm[13], rm[14], rm[15]);
        }
    }

    __syncthreads();
    if (t < 128) {                   // combine 8 (wave,half) slabs, float4-wide
        const float4* cb4 = (const float4*)&colbuf[0][0];
        float4 v = cb4[t];
#pragma unroll
        for (int s = 1; s < 8; ++s) v = min4(v, cb4[s * 128 + t]);
        *(float4*)(colpart + ((size_t)b * NSB + sub) * N + cb * COLS + t * 4) = v;
    }
}

__global__ __launch_bounds__(256) void finalize_kernel(
    const int* __restrict__ mask,
    const float* __restrict__ rowpart, const float* __restrict__ colpart,
    float* __restrict__ out)
{
    const int b = blockIdx.x & 15;
    const int q = blockIdx.x >> 4;   // quarter 0..3
    const int t = threadIdx.x;
    const int* mrow = mask + b * N;

    int cnt = 0;
    for (int i = t; i < N / 4; i += 256) {
        int4 mk = ((const int4*)mrow)[i];
        cnt += mk.x + mk.y + mk.z + mk.w;
    }

    const int p0 = q * 1024 + t * 4;
    const float* cp = colpart + (size_t)b * NSB * N + p0;      // 8 slabs
    const float* rp = rowpart + (size_t)b * NCB * 2 * N + p0;  // 16 slabs

    float4 mn = *(const float4*)cp;
    float4 rn = *(const float4*)rp;
#pragma unroll 8
    for (int pb = 1; pb < NCB * 2; ++pb) {
        rn = min4(rn, *(const float4*)(rp + (size_t)pb * N));
        if (pb < NSB)
            mn = min4(mn, *(const float4*)(cp + (size_t)pb * N));
    }
    int4 mk = *(const int4*)(mrow + p0);
    float s = (mk.x ? (mn.x + rn.x) : 0.f) + (mk.y ? (mn.y + rn.y) : 0.f)
            + (mk.z ? (mn.z + rn.z) : 0.f) + (mk.w ? (mn.w + rn.w) : 0.f);

    for (int off = 32; off > 0; off >>= 1) {
        s   += __shfl_down(s, off);
        cnt += __shfl_down(cnt, off);
    }
    __shared__ float rs[4];
    __shared__ int   rc[4];
    const int wv = t >> 6;
    if ((t & 63) == 0) { rs[wv] = s; rc[wv] = cnt; }
    __syncthreads();
    if (t == 0) {
        float S = rs[0] + rs[1] + rs[2] + rs[3];
        float C = (float)(rc[0] + rc[1] + rc[2] + rc[3]);
        atomicAdd(out, (S / C) * (1.0f / 16.0f));
    }
}

extern "C" void kernel_launch(void* const* d_in, const int* in_sizes, int n_in,
                              void* d_out, int out_size, void* d_ws, size_t ws_size,
                              hipStream_t stream) {
    const float* x    = (const float*)d_in[0];
    const float* y    = (const float*)d_in[1];
    const int*   mask = (const int*)d_in[2];

    float* rowpart = (float*)d_ws;                        // B*NCB*2*N = 4 MB
    float* colpart = rowpart + (size_t)B * NCB * 2 * N;   // B*NSB*N   = 2 MB

    chamfer_mfma<<<dim3(B * NCB * NSB), 256, 0, stream>>>(
        x, y, mask, rowpart, colpart, (float*)d_out);
    finalize_kernel<<<dim3(64), 256, 0, stream>>>(
        mask, rowpart, colpart, (float*)d_out);
}

// Round 13
// 85.963 us; speedup vs baseline: 1.0690x; 1.0110x over previous
//
#include <hip/hip_runtime.h>

typedef short bf16x8 __attribute__((ext_vector_type(8)));
typedef float f32x16 __attribute__((ext_vector_type(16)));

#define BIG_F 1e10f
constexpr int B = 16;
constexpr int N = 4096;
constexpr int COLS = 512;           // y-cols per block
constexpr int NCB = N / COLS;       // 8 col-blocks
constexpr int PASSES = 2;           // 256-row passes per block (2 streams each)
constexpr int SUBROWS = 512;        // rows per block
constexpr int NSB = N / SUBROWS;    // 8 row-superblocks

// truncating bf16 hi/lo split: v ~= hi + lo
__device__ __forceinline__ void split(float v, unsigned& h, unsigned& l) {
    unsigned hb = __float_as_uint(v) & 0xFFFF0000u;
    h = hb >> 16;
    float r = v - __uint_as_float(hb);
    l = __float_as_uint(r) >> 16;
}

__device__ __forceinline__ float min3f(float a, float b, float c) {
    return fminf(fminf(a, b), c);   // fuses to v_min3_f32
}

__device__ __forceinline__ float vmin16(f32x16 C) {
    float u0 = min3f(C[0], C[1], C[2]);
    float u1 = min3f(C[3], C[4], C[5]);
    float u2 = min3f(C[6], C[7], C[8]);
    float u3 = min3f(C[9], C[10], C[11]);
    float u4 = min3f(C[12], C[13], C[14]);
    return min3f(min3f(u0, u1, u2), fminf(u3, u4), C[15]);
}

__device__ __forceinline__ float4 min4(float4 a, float4 b) {
    return make_float4(fminf(a.x, b.x), fminf(a.y, b.y),
                       fminf(a.z, b.z), fminf(a.w, b.w));
}

// VALU-pipe cross-lane min via DPP (no ds-op). Validated exact (R8/R9/R11).
#define DPP_MIN(v, ctrl)                                                      \
    v = fminf(v, __int_as_float(__builtin_amdgcn_update_dpp(                  \
            __float_as_int(v), __float_as_int(v), (ctrl), 0xF, 0xF, false)))

// P[n,m] = xx[n] + yy[m] - 2 x_n . y_m (+BIG masked) via mfma_f32_32x32x16_bf16:
//   A_k(n) = [ah0..2, ah0..2, al0..2, al0..2, xxh, xxl, 1, 1]  (ah+al = -2x)
//   B_k(m) = [yh0..2, yl0..2, yh0..2, yl0..2, 1, 1, qh, ql]    (qh+ql = yy)
// R12/R13: ILP-2 probe. R11's body sits ~5x above its issue floor with nothing
// saturated -> per-wave dependency latency at 4 waves/SIMD. Each wave now
// runs TWO 32-row streams (afrA/afrB) against the SAME bf0/bf1 (B loaded
// once -> DS work halves per element; 2 independent MFMA->min chains/wave).
// Live set ~136-145 regs -> (256,3) budget 170 (R3/R8 spills were 140-live on
// a 128 budget; deliberate margin here). Grid stays 1024; 3/CU -> 1.33 gens.
// Spill tripwire: chamfer WRITE_SIZE must stay ~6 MB.
__global__ __launch_bounds__(256, 3) void chamfer_mfma(
    const float* __restrict__ x, const float* __restrict__ y,
    const int* __restrict__ mask,
    float* __restrict__ rowpart,   // [B][NCB][2][N] row-min partials (sset slabs)
    float* __restrict__ colpart,   // [B][NSB][N]    col-min partials (512 rows)
    float* __restrict__ out)
{
    const int blk = blockIdx.x;     // 0..1023
    const int b   = blk >> 6;
    const int cb  = (blk >> 3) & 7;
    const int sub = blk & 7;
    const int t   = threadIdx.x;

    __shared__ __align__(16) unsigned short Bpack[2][COLS][8];  // 16 KB
    __shared__ float colbuf[8][COLS];                           // 16 KB

    if (blk == 0 && t == 0) out[0] = 0.0f;   // finalize is the next dispatch

    const float* xb = x + (size_t)b * 3 * N;
    const float* yb = y + (size_t)b * 3 * N;
    const int*   mb = mask + b * N;

    // ---- pack this block's 512-col B slice (2 points/thread) ----
#pragma unroll
    for (int i = 0; i < 2; ++i) {
        int c = t + i * 256;
        int m = cb * COLS + c;
        float y0 = yb[m], y1 = yb[N + m], y2 = yb[2 * N + m];
        float madd = mb[m] ? 0.0f : BIG_F;
        float yy = fmaf(y2, y2, fmaf(y1, y1, y0 * y0)) + madd;
        unsigned h0, l0, h1, l1, h2, l2, qh, ql;
        split(y0, h0, l0);
        split(y1, h1, l1);
        split(y2, h2, l2);
        split(yy, qh, ql);
        unsigned u0 = h0 | (h1 << 16);
        unsigned u1 = h2 | (l0 << 16);
        unsigned u2 = l1 | (l2 << 16);
        uint4 w0 = { u0, u1, u2, u0 };
        uint4 w1 = { u1, u2, 0x3F803F80u, qh | (ql << 16) };
        *(uint4*)&Bpack[0][c][0] = w0;
        *(uint4*)&Bpack[1][c][0] = w1;
    }

    const int w    = t >> 6;    // wave 0..3
    const int L    = t & 63;
    const int half = L >> 5;    // k-half 0/1
    const int lc   = L & 31;

    __syncthreads();

    const unsigned short* Bb = &Bpack[half][lc][0];  // +p*512 shorts = col p*64+lc
    float* cacc0 = &colbuf[w * 2 + half][lc];        // thread-owned col-min slots

    const f32x16 z16 = {0.f,0.f,0.f,0.f,0.f,0.f,0.f,0.f,
                        0.f,0.f,0.f,0.f,0.f,0.f,0.f,0.f};

    auto buildA = [&](int n) -> bf16x8 {
        float x0 = xb[n], x1 = xb[N + n], x2 = xb[2 * N + n];
        float madd = mb[n] ? 0.0f : BIG_F;
        float xx = fmaf(x2, x2, fmaf(x1, x1, x0 * x0)) + madd;
        unsigned h0, l0, h1, l1, h2, l2, xh, xl;
        split(-2.0f * x0, h0, l0);
        split(-2.0f * x1, h1, l1);
        split(-2.0f * x2, h2, l2);
        split(xx, xh, xl);
        uint4 wa;
        wa.x = half ? (l2 | (l0 << 16)) : (h0 | (h1 << 16));
        wa.y = half ? (l1 | (l2 << 16)) : (h2 | (h0 << 16));
        wa.z = half ? (xh | (xl << 16)) : (h1 | (h2 << 16));
        wa.w = half ? 0x3F803F80u       : (l0 | (l1 << 16));
        return *(bf16x8*)&wa;
    };

#pragma unroll 1
    for (int pass = 0; pass < PASSES; ++pass) {
        const int rowbase = sub * SUBROWS + pass * 256;
        // two 32-row streams per wave: rows rowbase+w*32 (A), +128 (B)
        bf16x8 afrA = buildA(rowbase + w * 32 + lc);
        bf16x8 afrB = buildA(rowbase + 128 + w * 32 + lc);

        float rmA[16], rmB[16];
#pragma unroll
        for (int r = 0; r < 16; ++r) { rmA[r] = 1e30f; rmB[r] = 1e30f; }

#pragma unroll 1
        for (int p = 0; p < 8; ++p) {          // 8 col-pairs of 32 = 512 cols
            bf16x8 bf0 = *(const bf16x8*)(Bb + p * 512);
            bf16x8 bf1 = *(const bf16x8*)(Bb + p * 512 + 256);
            f32x16 C0a = __builtin_amdgcn_mfma_f32_32x32x16_bf16(afrA, bf0, z16, 0, 0, 0);
            f32x16 C0b = __builtin_amdgcn_mfma_f32_32x32x16_bf16(afrB, bf0, z16, 0, 0, 0);
            f32x16 C1a = __builtin_amdgcn_mfma_f32_32x32x16_bf16(afrA, bf1, z16, 0, 0, 0);
            f32x16 C1b = __builtin_amdgcn_mfma_f32_32x32x16_bf16(afrB, bf1, z16, 0, 0, 0);
            // C[r]: row = base + (r&3)+8*(r>>2)+4*half, col = p*64(+32)+lc
#pragma unroll
            for (int r = 0; r < 16; ++r) {
                rmA[r] = min3f(rmA[r], C0a[r], C1a[r]);
                rmB[r] = min3f(rmB[r], C0b[r], C1b[r]);
            }
            // col partials: min over both streams' 16-row halves, rmw LDS
            float v0 = fminf(vmin16(C0a), vmin16(C0b));
            float v1 = fminf(vmin16(C1a), vmin16(C1b));
            if (pass == 0) {
                cacc0[p * 64]      = v0;
                cacc0[p * 64 + 32] = v1;
            } else {
                cacc0[p * 64]      = fminf(cacc0[p * 64],      v0);
                cacc0[p * 64 + 32] = fminf(cacc0[p * 64 + 32], v1);
            }
        }

        // ---- row-min over each 16-lane group, entirely on the VALU pipe ----
#pragma unroll
        for (int r = 0; r < 16; ++r) {
            DPP_MIN(rmA[r], 0xB1);   DPP_MIN(rmB[r], 0xB1);   // quad xor1
            DPP_MIN(rmA[r], 0x4E);   DPP_MIN(rmB[r], 0x4E);   // quad xor2
            DPP_MIN(rmA[r], 0x124);  DPP_MIN(rmB[r], 0x124);  // row_ror:4
            DPP_MIN(rmA[r], 0x128);  DPP_MIN(rmB[r], 0x128);  // row_ror:8
        }
        if ((lc & 15) == 0) {        // lanes 0,16,32,48: (half, col-subset)
            int sset = lc >> 4;
            float* rpA = rowpart + (((size_t)(b * NCB + cb)) * 2 + sset) * N
                       + rowbase + w * 32 + half * 4;
            float* rpB = rpA + 128;
            *(float4*)(rpA +  0) = make_float4(rmA[0],  rmA[1],  rmA[2],  rmA[3]);
            *(float4*)(rpA +  8) = make_float4(rmA[4],  rmA[5],  rmA[6],  rmA[7]);
            *(float4*)(rpA + 16) = make_float4(rmA[8],  rmA[9],  rmA[10], rmA[11]);
            *(float4*)(rpA + 24) = make_float4(rmA[12], rmA[13], rmA[14], rmA[15]);
            *(float4*)(rpB +  0) = make_float4(rmB[0],  rmB[1],  rmB[2],  rmB[3]);
            *(float4*)(rpB +  8) = make_float4(rmB[4],  rmB[5],  rmB[6],  rmB[7]);
            *(float4*)(rpB + 16) = make_float4(rmB[8],  rmB[9],  rmB[10], rmB[11]);
            *(float4*)(rpB + 24) = make_float4(rmB[12], rmB[13], rmB[14], rmB[15]);
        }
    }

    __syncthreads();
    if (t < 128) {                   // combine 8 (wave,half) slabs, float4-wide
        const float4* cb4 = (const float4*)&colbuf[0][0];
        float4 v = cb4[t];
#pragma unroll
        for (int s = 1; s < 8; ++s) v = min4(v, cb4[s * 128 + t]);
        *(float4*)(colpart + ((size_t)b * NSB + sub) * N + cb * COLS + t * 4) = v;
    }
}

__global__ __launch_bounds__(256) void finalize_kernel(
    const int* __restrict__ mask,
    const float* __restrict__ rowpart, const float* __restrict__ colpart,
    float* __restrict__ out)
{
    const int b = blockIdx.x & 15;
    const int q = blockIdx.x >> 4;   // quarter 0..3
    const int t = threadIdx.x;
    const int* mrow = mask + b * N;

    int cnt = 0;
    for (int i = t; i < N / 4; i += 256) {
        int4 mk = ((const int4*)mrow)[i];
        cnt += mk.x + mk.y + mk.z + mk.w;
    }

    const int p0 = q * 1024 + t * 4;
    const float* cp = colpart + (size_t)b * NSB * N + p0;      // 8 slabs
    const float* rp = rowpart + (size_t)b * NCB * 2 * N + p0;  // 16 slabs

    float4 mn = *(const float4*)cp;
    float4 rn = *(const float4*)rp;
#pragma unroll 8
    for (int pb = 1; pb < NCB * 2; ++pb) {
        rn = min4(rn, *(const float4*)(rp + (size_t)pb * N));
        if (pb < NSB)
            mn = min4(mn, *(const float4*)(cp + (size_t)pb * N));
    }
    int4 mk = *(const int4*)(mrow + p0);
    float s = (mk.x ? (mn.x + rn.x) : 0.f) + (mk.y ? (mn.y + rn.y) : 0.f)
            + (mk.z ? (mn.z + rn.z) : 0.f) + (mk.w ? (mn.w + rn.w) : 0.f);

    for (int off = 32; off > 0; off >>= 1) {
        s   += __shfl_down(s, off);
        cnt += __shfl_down(cnt, off);
    }
    __shared__ float rs[4];
    __shared__ int   rc[4];
    const int wv = t >> 6;
    if ((t & 63) == 0) { rs[wv] = s; rc[wv] = cnt; }
    __syncthreads();
    if (t == 0) {
        float S = rs[0] + rs[1] + rs[2] + rs[3];
        float C = (float)(rc[0] + rc[1] + rc[2] + rc[3]);
        atomicAdd(out, (S / C) * (1.0f / 16.0f));
    }
}

extern "C" void kernel_launch(void* const* d_in, const int* in_sizes, int n_in,
                              void* d_out, int out_size, void* d_ws, size_t ws_size,
                              hipStream_t stream) {
    const float* x    = (const float*)d_in[0];
    const float* y    = (const float*)d_in[1];
    const int*   mask = (const int*)d_in[2];

    float* rowpart = (float*)d_ws;                        // B*NCB*2*N = 4 MB
    float* colpart = rowpart + (size_t)B * NCB * 2 * N;   // B*NSB*N   = 2 MB

    chamfer_mfma<<<dim3(B * NCB * NSB), 256, 0, stream>>>(
        x, y, mask, rowpart, colpart, (float*)d_out);
    finalize_kernel<<<dim3(64), 256, 0, stream>>>(
        mask, rowpart, colpart, (float*)d_out);
}